// Round 3
// baseline (241.031 us; speedup 1.0000x reference)
//
#include <hip/hip_runtime.h>
#include <stdint.h>

#define D_MODEL 1024
#define NH      16
#define DKH     64
#define BATCH   2
#define SEQ     2048
#define M_TOK   (BATCH*SEQ)   // 4096

typedef __attribute__((ext_vector_type(8))) short bf16x8;   // 8 bf16 = 4 VGPRs
typedef __attribute__((ext_vector_type(4))) float f32x4;    // MFMA C/D

// fp32 -> bf16, round-to-nearest-even
__device__ __forceinline__ uint16_t f2b(float f) {
  uint32_t u = __builtin_bit_cast(uint32_t, f);
  return (uint16_t)((u + 0x7FFFu + ((u >> 16) & 1u)) >> 16);
}

// async global->LDS, 16B per lane. HW writes LDS at wave-uniform base + lane*16.
__device__ __forceinline__ void gl2lds16(const uint16_t* g, uint16_t* l) {
  __builtin_amdgcn_global_load_lds(
      (const __attribute__((address_space(1))) void*)g,
      (__attribute__((address_space(3))) void*)l, 16, 0, 0);
}

// ---------------- convert X to bf16 ----------------
__global__ void convx(const float* __restrict__ X, uint16_t* __restrict__ Xb) {
  int i = (blockIdx.x * 256 + threadIdx.x) * 8;
  float4 a = *(const float4*)(X + i);
  float4 b = *(const float4*)(X + i + 4);
  uint16_t tmp[8] = {f2b(a.x), f2b(a.y), f2b(a.z), f2b(a.w),
                     f2b(b.x), f2b(b.y), f2b(b.z), f2b(b.w)};
  *(uint4*)(Xb + i) = *(const uint4*)tmp;
}

// ------------- transpose + convert W ([K][N] fp32 -> [N][K] bf16) -------------
__global__ void wtrans(const float* __restrict__ W0, const float* __restrict__ W1,
                       const float* __restrict__ W2, const float* __restrict__ W3,
                       uint16_t* __restrict__ T0, uint16_t* __restrict__ T1,
                       uint16_t* __restrict__ T2, uint16_t* __restrict__ T3) {
  __shared__ float tile[32][33];
  int z = blockIdx.z;
  const float* W = (z == 0) ? W0 : (z == 1) ? W1 : (z == 2) ? W2 : W3;
  uint16_t*    T = (z == 0) ? T0 : (z == 1) ? T1 : (z == 2) ? T2 : T3;
  int k0 = blockIdx.x * 32, n0 = blockIdx.y * 32;
  int tx = threadIdx.x, ty = threadIdx.y;
  tile[ty][tx] = W[(size_t)(k0 + ty) * D_MODEL + n0 + tx];
  __syncthreads();
  T[(size_t)(n0 + ty) * D_MODEL + k0 + tx] = f2b(tile[tx][ty]);
}

// ---------------- 128x128 bf16 MFMA GEMM core, XOR-swizzled staging ----------------
// Staging permutes the global 16B-chunk per lane (chunk' = chunk ^ ((row>>1)&3)) so
// the lane-contiguous global_load_lds layout becomes bank-conflict-free for the
// 16-lane-row-stride b128 fragment reads (read chunk = g ^ ((qi>>1)&3)).
// SWAP=true swaps MFMA operands: C col=token, row=channel (4 consecutive channels/lane).
template <bool SWAP>
__device__ __forceinline__ void gemm_core(const uint16_t* __restrict__ A,
                                          const uint16_t* __restrict__ BT,
                                          uint16_t* As, uint16_t* Bs,
                                          int m0, int n0, int kBeg, int kEnd,
                                          f32x4 (&acc)[4][4]) {
  const int t    = threadIdx.x;
  const int lane = t & 63;
  const int qi   = lane & 15, g = lane >> 4;
  const int wm   = (t >> 7) & 1;
  const int wn   = (t >> 6) & 1;
  const int srow = t >> 2;                       // staging row 0..63
  const int sc   = (t & 3) ^ ((t >> 3) & 3);     // swizzled global chunk
  const int wbase = t & 192;
  const int rch  = (g ^ ((qi >> 1) & 3)) * 8;    // swizzled read chunk (elems)

  for (int k0 = kBeg; k0 < kEnd; k0 += 32) {
    __syncthreads();
#pragma unroll
    for (int j = 0; j < 2; j++) {
      int row = j * 64 + srow;
      gl2lds16(A  + (size_t)(m0 + row) * D_MODEL + k0 + sc * 8,
               As + (j * 256 + wbase) * 8);
      gl2lds16(BT + (size_t)(n0 + row) * D_MODEL + k0 + sc * 8,
               Bs + (j * 256 + wbase) * 8);
    }
    __syncthreads();
    bf16x8 af[4], bf[4];
#pragma unroll
    for (int i = 0; i < 4; i++) {
      af[i] = *(const bf16x8*)(As + (wm * 64 + i * 16 + qi) * 32 + rch);
      bf[i] = *(const bf16x8*)(Bs + (wn * 64 + i * 16 + qi) * 32 + rch);
    }
#pragma unroll
    for (int i = 0; i < 4; i++)
#pragma unroll
      for (int j = 0; j < 4; j++)
        acc[i][j] = SWAP
          ? __builtin_amdgcn_mfma_f32_16x16x32_bf16(bf[j], af[i], acc[i][j], 0, 0, 0)
          : __builtin_amdgcn_mfma_f32_16x16x32_bf16(af[i], bf[j], acc[i][j], 0, 0, 0);
  }
}

// ---------------- fused QKV projection ----------------
// z=0 -> Q scaled by log2(e)/8 (bf16 [4096][1024]), z=1 -> K, z=2 -> V transposed
// per head: Vt[(b*16+h)*64 + d][s] via LDS transpose for coalesced writes.
__global__ __launch_bounds__(256) void qkv_gemm(
    const uint16_t* __restrict__ Xb,
    const uint16_t* __restrict__ WqT, const uint16_t* __restrict__ WkT,
    const uint16_t* __restrict__ WvT,
    const float* __restrict__ bq, const float* __restrict__ bk,
    const float* __restrict__ bv,
    uint16_t* __restrict__ Qo, uint16_t* __restrict__ Ko, uint16_t* __restrict__ Vt) {
  __shared__ __align__(16) uint16_t smem[17408];   // As/Bs (8192) aliased with T (17408)
  uint16_t* As = smem;
  uint16_t* Bs = smem + 4096;
  uint16_t* T  = smem;                             // [128 ch][136] transpose buf (z==2)
  const int z = blockIdx.z;
  const uint16_t* BT  = (z == 0) ? WqT : (z == 1) ? WkT : WvT;
  const float*   bias = (z == 0) ? bq  : (z == 1) ? bk  : bv;
  const int m0 = blockIdx.x * 128, n0 = blockIdx.y * 128;
  const int lane = threadIdx.x & 63, qi = lane & 15, g = lane >> 4;
  const int wm = (threadIdx.x >> 7) & 1, wn = (threadIdx.x >> 6) & 1;
  const float l2e = 1.4426950408889634f * 0.125f;  // log2(e)/sqrt(dk), folded into Q

  const f32x4 ZERO = {0.f, 0.f, 0.f, 0.f};
  f32x4 acc[4][4];
#pragma unroll
  for (int i = 0; i < 4; i++)
#pragma unroll
    for (int j = 0; j < 4; j++) acc[i][j] = ZERO;

  if (z == 2) {
    gemm_core<false>(Xb, BT, As, Bs, m0, n0, 0, D_MODEL, acc);
    __syncthreads();  // all waves done with As/Bs before T overwrite
    // C: col = channel (qi), rows = 4 consecutive tokens -> T[ch][token] (stride 136)
#pragma unroll
    for (int i = 0; i < 4; i++) {
      int tok = wm * 64 + i * 16 + g * 4;
#pragma unroll
      for (int j = 0; j < 4; j++) {
        int ch = wn * 64 + j * 16 + qi;
        float bb = bias[n0 + ch];
        uint32_t lo = (uint32_t)f2b(acc[i][j][0] + bb) | ((uint32_t)f2b(acc[i][j][1] + bb) << 16);
        uint32_t hi = (uint32_t)f2b(acc[i][j][2] + bb) | ((uint32_t)f2b(acc[i][j][3] + bb) << 16);
        uint2 pk = {lo, hi};
        *(uint2*)(T + ch * 136 + tok) = pk;
      }
    }
    __syncthreads();
    // coalesced write-out: thread -> (channel, s-half), 128B contiguous per thread
    {
      int ch = threadIdx.x >> 1, sh = threadIdx.x & 1;
      const uint16_t* src = T + ch * 136 + sh * 64;
      int bidx = m0 >> 11;
      uint16_t* dst = Vt + ((size_t)(bidx * D_MODEL + n0 + ch)) * SEQ + (m0 & 2047) + sh * 64;
#pragma unroll
      for (int u = 0; u < 8; u++)
        *(uint4*)(dst + u * 8) = *(const uint4*)(src + u * 8);
    }
  } else {
    gemm_core<true>(Xb, BT, As, Bs, m0, n0, 0, D_MODEL, acc);
    // swapped C: col = token (qi), rows = 4 consecutive channels -> one uint2/tile
    uint16_t* O = z ? Ko : Qo;
    const float osc = (z == 0) ? l2e : 1.0f;
#pragma unroll
    for (int i = 0; i < 4; i++) {
      size_t tok = m0 + wm * 64 + i * 16 + qi;
#pragma unroll
      for (int j = 0; j < 4; j++) {
        int ch = n0 + wn * 64 + j * 16 + g * 4;
        float4 bb = *(const float4*)(bias + ch);
        uint32_t lo = (uint32_t)f2b((acc[i][j][0] + bb.x) * osc) |
                      ((uint32_t)f2b((acc[i][j][1] + bb.y) * osc) << 16);
        uint32_t hi = (uint32_t)f2b((acc[i][j][2] + bb.z) * osc) |
                      ((uint32_t)f2b((acc[i][j][3] + bb.w) * osc) << 16);
        uint2 pk = {lo, hi};
        *(uint2*)(O + tok * D_MODEL + ch) = pk;
      }
    }
  }
}

// ---------------- output projection, split-K x2, fp32 atomic accumulate ----------------
__global__ __launch_bounds__(256) void oproj_gemm(
    const uint16_t* __restrict__ Ab, const uint16_t* __restrict__ WoT,
    const float* __restrict__ bo, float* __restrict__ out) {
  __shared__ __align__(16) uint16_t As[128 * 32];
  __shared__ __align__(16) uint16_t Bs[128 * 32];
  const int m0 = blockIdx.x * 128, n0 = blockIdx.y * 128;
  const int kz = blockIdx.z;
  const f32x4 ZERO = {0.f, 0.f, 0.f, 0.f};
  f32x4 acc[4][4];
#pragma unroll
  for (int i = 0; i < 4; i++)
#pragma unroll
    for (int j = 0; j < 4; j++) acc[i][j] = ZERO;

  gemm_core<false>(Ab, WoT, As, Bs, m0, n0, kz * 512, kz * 512 + 512, acc);

  const int lane = threadIdx.x & 63;
  const int wm = (threadIdx.x >> 7) & 1, wn = (threadIdx.x >> 6) & 1;
#pragma unroll
  for (int i = 0; i < 4; i++) {
    int row = m0 + wm * 64 + i * 16 + ((lane >> 4) << 2);
#pragma unroll
    for (int j = 0; j < 4; j++) {
      int col = n0 + wn * 64 + j * 16 + (lane & 15);
      float bb = kz ? 0.f : bo[col];
#pragma unroll
      for (int r = 0; r < 4; r++)
        atomicAdd(&out[(size_t)(row + r) * D_MODEL + col], acc[i][j][r] + bb);
    }
  }
}

// ---------------- flash attention, static softmax, transposed MFMA ----------------
// Q pre-scaled by log2(e)/sqrt(dk) -> P = exp2(sacc) directly. P stored truncated
// (RTZ) to bf16; l sums the truncated values so normalization is exact w.r.t. the
// P actually used in PV. XOR-swizzled K/V/Q staging kills the 8-way b128 conflicts.
__global__ __launch_bounds__(256) void attn_fwd(
    const uint16_t* __restrict__ Q, const uint16_t* __restrict__ K,
    const uint16_t* __restrict__ Vt, uint16_t* __restrict__ O) {
  __shared__ __align__(16) uint16_t sm[25600];   // 51200 B
  uint16_t* Q0 = sm;            // [128][32] d 0..31
  uint16_t* Q1 = sm + 4096;     // [128][32] d 32..63
  uint16_t* K0 = sm + 8192;     // [64][32]
  uint16_t* K1 = sm + 10240;
  uint16_t* V0 = sm + 12288;    // [64 d][32 kk]
  uint16_t* V1 = sm + 14336;
  uint16_t* Ps = sm + 16384;    // [128 q][72]

  const int t = threadIdx.x, lane = t & 63, w = t >> 6;
  const int g = lane >> 4, qi = lane & 15;
  const int wbase = t & 192;
  const int sc = (t & 3) ^ ((t >> 3) & 3);       // swizzled staging chunk
  const int rch = (g ^ ((qi >> 1) & 3)) * 8;     // swizzled read chunk (elems)
  const int q0 = blockIdx.x * 128;
  const int bh = blockIdx.y, b = bh >> 4, h = bh & 15;
  const uint16_t* Qp = Q + (size_t)b * SEQ * D_MODEL + h * DKH;
  const uint16_t* Kp = K + (size_t)b * SEQ * D_MODEL + h * DKH;
  const uint16_t* Vp = Vt + (size_t)bh * DKH * SEQ;

  // stage Q tile once: 128 rows x 64 d, two stride-32 halves
#pragma unroll
  for (int hs = 0; hs < 2; hs++) {
    uint16_t* Qs = hs ? Q1 : Q0;
#pragma unroll
    for (int j = 0; j < 2; j++) {
      int row = j * 64 + (t >> 2);
      gl2lds16(Qp + (size_t)(q0 + row) * D_MODEL + hs * 32 + sc * 8,
               Qs + (j * 256 + wbase) * 8);
    }
  }

  float lsum[2] = {0.f, 0.f};
  const f32x4 ZERO = {0.f, 0.f, 0.f, 0.f};
  f32x4 oaccT[4][2];   // [d-tile][q-tile]
#pragma unroll
  for (int d = 0; d < 4; d++)
#pragma unroll
    for (int i = 0; i < 2; i++) oaccT[d][i] = ZERO;

  for (int kt = 0; kt < SEQ / 64; kt++) {
    __syncthreads();
    {
      int row = t >> 2, c8 = sc * 8;
      const uint16_t* Kr = Kp + (size_t)(kt * 64 + row) * D_MODEL;
      const uint16_t* Vr = Vp + (size_t)row * SEQ + kt * 64;
      gl2lds16(Kr + c8,       K0 + wbase * 8);
      gl2lds16(Kr + 32 + c8,  K1 + wbase * 8);
      gl2lds16(Vr + c8,       V0 + wbase * 8);
      gl2lds16(Vr + 32 + c8,  V1 + wbase * 8);
    }
    __syncthreads();

    // S^T[kk][q] = K Q^T (Q pre-scaled -> log2-domain scores)
    f32x4 sacc[4][2];
#pragma unroll
    for (int j = 0; j < 4; j++)
#pragma unroll
      for (int i = 0; i < 2; i++) sacc[j][i] = ZERO;
#pragma unroll
    for (int ks = 0; ks < 2; ks++) {
      const uint16_t* Ksb = ks ? K1 : K0;
      const uint16_t* Qsb = ks ? Q1 : Q0;
      bf16x8 kf[4], qf[2];
#pragma unroll
      for (int j = 0; j < 4; j++)
        kf[j] = *(const bf16x8*)(Ksb + (j * 16 + qi) * 32 + rch);
#pragma unroll
      for (int i = 0; i < 2; i++)
        qf[i] = *(const bf16x8*)(Qsb + (w * 32 + i * 16 + qi) * 32 + rch);
#pragma unroll
      for (int j = 0; j < 4; j++)
#pragma unroll
        for (int i = 0; i < 2; i++)
          sacc[j][i] = __builtin_amdgcn_mfma_f32_16x16x32_bf16(kf[j], qf[i], sacc[j][i], 0, 0, 0);
    }

    // P = exp2(s), truncate to bf16 (RTZ); l sums the truncated values (exact norm)
#pragma unroll
    for (int i = 0; i < 2; i++) {
      uint16_t* Pr = Ps + (w * 32 + i * 16 + qi) * 72;
#pragma unroll
      for (int j = 0; j < 4; j++) {
        uint32_t u0 = __builtin_bit_cast(uint32_t, __builtin_amdgcn_exp2f(sacc[j][i][0])) & 0xffff0000u;
        uint32_t u1 = __builtin_bit_cast(uint32_t, __builtin_amdgcn_exp2f(sacc[j][i][1])) & 0xffff0000u;
        uint32_t u2 = __builtin_bit_cast(uint32_t, __builtin_amdgcn_exp2f(sacc[j][i][2])) & 0xffff0000u;
        uint32_t u3 = __builtin_bit_cast(uint32_t, __builtin_amdgcn_exp2f(sacc[j][i][3])) & 0xffff0000u;
        lsum[i] += (__builtin_bit_cast(float, u0) + __builtin_bit_cast(float, u1)) +
                   (__builtin_bit_cast(float, u2) + __builtin_bit_cast(float, u3));
        uint2 pk = {(u0 >> 16) | u1, (u2 >> 16) | u3};
        *(uint2*)(Pr + j * 16 + g * 4) = pk;
      }
    }
    __syncthreads();

    // O^T[d][q] += V^T P^T
#pragma unroll
    for (int ks = 0; ks < 2; ks++) {
      const uint16_t* Vsb = ks ? V1 : V0;
      bf16x8 vf[4], pf[2];
#pragma unroll
      for (int d = 0; d < 4; d++)
        vf[d] = *(const bf16x8*)(Vsb + (d * 16 + qi) * 32 + rch);
#pragma unroll
      for (int i = 0; i < 2; i++)
        pf[i] = *(const bf16x8*)(Ps + (w * 32 + i * 16 + qi) * 72 + ks * 32 + g * 8);
#pragma unroll
      for (int d = 0; d < 4; d++)
#pragma unroll
        for (int i = 0; i < 2; i++)
          oaccT[d][i] = __builtin_amdgcn_mfma_f32_16x16x32_bf16(vf[d], pf[i], oaccT[d][i], 0, 0, 0);
    }
  }

  // final l reduction over the 4 lane-groups holding the same q
#pragma unroll
  for (int i = 0; i < 2; i++) {
    lsum[i] += __shfl_xor(lsum[i], 16, 64);
    lsum[i] += __shfl_xor(lsum[i], 32, 64);
  }
  float rl[2] = {1.f / lsum[0], 1.f / lsum[1]};

  // epilogue: O[q][h*64+d] = O^T/l (RNE), 4 consecutive d per 8B store
#pragma unroll
  for (int i = 0; i < 2; i++) {
    size_t row = (size_t)b * SEQ + q0 + w * 32 + i * 16 + qi;
#pragma unroll
    for (int d = 0; d < 4; d++) {
      uint32_t lo = (uint32_t)f2b(oaccT[d][i][0] * rl[i]) |
                    ((uint32_t)f2b(oaccT[d][i][1] * rl[i]) << 16);
      uint32_t hi = (uint32_t)f2b(oaccT[d][i][2] * rl[i]) |
                    ((uint32_t)f2b(oaccT[d][i][3] * rl[i]) << 16);
      uint2 pk = {lo, hi};
      *(uint2*)(O + row * D_MODEL + h * DKH + d * 16 + g * 4) = pk;
    }
  }
}

extern "C" void kernel_launch(void* const* d_in, const int* in_sizes, int n_in,
                              void* d_out, int out_size, void* d_ws, size_t ws_size,
                              hipStream_t stream) {
  (void)in_sizes; (void)n_in; (void)out_size; (void)ws_size;
  const float* X  = (const float*)d_in[0];
  const float* Wq = (const float*)d_in[1];
  const float* bq = (const float*)d_in[2];
  const float* Wk = (const float*)d_in[3];
  const float* bk = (const float*)d_in[4];
  const float* Wv = (const float*)d_in[5];
  const float* bv = (const float*)d_in[6];
  const float* Wo = (const float*)d_in[7];
  const float* bo = (const float*)d_in[8];
  float* out = (float*)d_out;

  char* p = (char*)d_ws;
  uint16_t* Xb  = (uint16_t*)p; p += (size_t)M_TOK * D_MODEL * 2;
  uint16_t* WqT = (uint16_t*)p; p += (size_t)D_MODEL * D_MODEL * 2;
  uint16_t* WkT = (uint16_t*)p; p += (size_t)D_MODEL * D_MODEL * 2;
  uint16_t* WvT = (uint16_t*)p; p += (size_t)D_MODEL * D_MODEL * 2;
  uint16_t* WoT = (uint16_t*)p; p += (size_t)D_MODEL * D_MODEL * 2;
  uint16_t* Qw  = (uint16_t*)p; p += (size_t)M_TOK * D_MODEL * 2;
  uint16_t* Kw  = (uint16_t*)p; p += (size_t)M_TOK * D_MODEL * 2;
  uint16_t* Vt  = (uint16_t*)p; p += (size_t)M_TOK * D_MODEL * 2;
  uint16_t* Ob  = (uint16_t*)p; p += (size_t)M_TOK * D_MODEL * 2;

  hipMemsetAsync(out, 0, (size_t)M_TOK * D_MODEL * sizeof(float), stream);
  convx<<<(M_TOK * D_MODEL) / (256 * 8), 256, 0, stream>>>(X, Xb);
  wtrans<<<dim3(32, 32, 4), dim3(32, 32), 0, stream>>>(Wq, Wk, Wv, Wo, WqT, WkT, WvT, WoT);
  qkv_gemm<<<dim3(32, 8, 3), 256, 0, stream>>>(Xb, WqT, WkT, WvT, bq, bk, bv, Qw, Kw, Vt);
  attn_fwd<<<dim3(SEQ / 128, BATCH * NH), 256, 0, stream>>>(Qw, Kw, Vt, Ob);
  oproj_gemm<<<dim3(32, 8, 2), 256, 0, stream>>>(Ob, WoT, bo, out);
}

// Round 4
// 208.326 us; speedup vs baseline: 1.1570x; 1.1570x over previous
//
#include <hip/hip_runtime.h>
#include <stdint.h>

#define D_MODEL 1024
#define NH      16
#define DKH     64
#define BATCH   2
#define SEQ     2048
#define M_TOK   (BATCH*SEQ)   // 4096

typedef __attribute__((ext_vector_type(8))) short bf16x8;   // 8 bf16 = 4 VGPRs
typedef __attribute__((ext_vector_type(4))) float f32x4;    // MFMA C/D

// fp32 -> bf16, round-to-nearest-even
__device__ __forceinline__ uint16_t f2b(float f) {
  uint32_t u = __builtin_bit_cast(uint32_t, f);
  return (uint16_t)((u + 0x7FFFu + ((u >> 16) & 1u)) >> 16);
}

// async global->LDS, 16B per lane. HW writes LDS at wave-uniform base + lane*16.
__device__ __forceinline__ void gl2lds16(const uint16_t* g, uint16_t* l) {
  __builtin_amdgcn_global_load_lds(
      (const __attribute__((address_space(1))) void*)g,
      (__attribute__((address_space(3))) void*)l, 16, 0, 0);
}

// ---------------- convert X to bf16 ----------------
__global__ void convx(const float* __restrict__ X, uint16_t* __restrict__ Xb) {
  int i = (blockIdx.x * 256 + threadIdx.x) * 8;
  float4 a = *(const float4*)(X + i);
  float4 b = *(const float4*)(X + i + 4);
  uint16_t tmp[8] = {f2b(a.x), f2b(a.y), f2b(a.z), f2b(a.w),
                     f2b(b.x), f2b(b.y), f2b(b.z), f2b(b.w)};
  *(uint4*)(Xb + i) = *(const uint4*)tmp;
}

// ------------- transpose + convert W ([K][N] fp32 -> [N][K] bf16) -------------
__global__ void wtrans(const float* __restrict__ W0, const float* __restrict__ W1,
                       const float* __restrict__ W2, const float* __restrict__ W3,
                       uint16_t* __restrict__ T0, uint16_t* __restrict__ T1,
                       uint16_t* __restrict__ T2, uint16_t* __restrict__ T3) {
  __shared__ float tile[32][33];
  int z = blockIdx.z;
  const float* W = (z == 0) ? W0 : (z == 1) ? W1 : (z == 2) ? W2 : W3;
  uint16_t*    T = (z == 0) ? T0 : (z == 1) ? T1 : (z == 2) ? T2 : T3;
  int k0 = blockIdx.x * 32, n0 = blockIdx.y * 32;
  int tx = threadIdx.x, ty = threadIdx.y;
  tile[ty][tx] = W[(size_t)(k0 + ty) * D_MODEL + n0 + tx];
  __syncthreads();
  T[(size_t)(n0 + ty) * D_MODEL + k0 + tx] = f2b(tile[tx][ty]);
}

// ------ 128x128 bf16 MFMA GEMM core: double-buffered LDS, 1 barrier/K-step ------
// Prefetch of step k+1 is issued right after the barrier that publishes step k,
// so the next barrier's vmcnt(0) drain waits on a load that has been in flight
// for a whole compute phase. XOR-swizzled staging (chunk' = chunk ^ ((row>>1)&3))
// keeps the b128 fragment reads ~conflict-free despite the lane-contiguous
// global_load_lds layout. As/Bs regions are [2 buf][128 rows][32 elems].
// SWAP=true swaps MFMA operands: C col=token, row=channel (4 consecutive ch/lane).
template <bool SWAP>
__device__ __forceinline__ void gemm_core(const uint16_t* __restrict__ A,
                                          const uint16_t* __restrict__ BT,
                                          uint16_t* As, uint16_t* Bs,
                                          int m0, int n0, int kBeg, int kEnd,
                                          f32x4 (&acc)[4][4]) {
  const int t    = threadIdx.x;
  const int lane = t & 63;
  const int qi   = lane & 15, g = lane >> 4;
  const int wm   = (t >> 7) & 1;
  const int wn   = (t >> 6) & 1;
  const int srow = t >> 2;                       // staging row 0..63
  const int sc   = (t & 3) ^ ((t >> 3) & 3);     // swizzled global chunk
  const int wbase = t & 192;
  const int rch  = (g ^ ((qi >> 1) & 3)) * 8;    // swizzled read chunk (elems)

  const uint16_t* Ag = A  + (size_t)(m0 + srow) * D_MODEL + sc * 8;
  const uint16_t* Bg = BT + (size_t)(n0 + srow) * D_MODEL + sc * 8;

  // initial stage into buf 0
#pragma unroll
  for (int j = 0; j < 2; j++) {
    gl2lds16(Ag + (size_t)j * 64 * D_MODEL + kBeg, As + (j * 256 + wbase) * 8);
    gl2lds16(Bg + (size_t)j * 64 * D_MODEL + kBeg, Bs + (j * 256 + wbase) * 8);
  }

  int cur = 0;
  for (int k0 = kBeg; k0 < kEnd; k0 += 32) {
    __syncthreads();   // publishes buf[cur] (vmcnt drain) + all reads of buf[cur^1] done
    int kn = k0 + 32;
    if (kn < kEnd) {   // prefetch next step into the other buffer (in flight across compute)
      int nb = (cur ^ 1) * 4096;
#pragma unroll
      for (int j = 0; j < 2; j++) {
        gl2lds16(Ag + (size_t)j * 64 * D_MODEL + kn, As + nb + (j * 256 + wbase) * 8);
        gl2lds16(Bg + (size_t)j * 64 * D_MODEL + kn, Bs + nb + (j * 256 + wbase) * 8);
      }
    }
    const uint16_t* Ab = As + cur * 4096;
    const uint16_t* Bb = Bs + cur * 4096;
    bf16x8 af[4], bf[4];
#pragma unroll
    for (int i = 0; i < 4; i++) {
      af[i] = *(const bf16x8*)(Ab + (wm * 64 + i * 16 + qi) * 32 + rch);
      bf[i] = *(const bf16x8*)(Bb + (wn * 64 + i * 16 + qi) * 32 + rch);
    }
#pragma unroll
    for (int i = 0; i < 4; i++)
#pragma unroll
      for (int j = 0; j < 4; j++)
        acc[i][j] = SWAP
          ? __builtin_amdgcn_mfma_f32_16x16x32_bf16(bf[j], af[i], acc[i][j], 0, 0, 0)
          : __builtin_amdgcn_mfma_f32_16x16x32_bf16(af[i], bf[j], acc[i][j], 0, 0, 0);
    cur ^= 1;
  }
}

// ---------------- fused QKV projection ----------------
// z=0 -> Q scaled by log2(e)/8 (bf16 [4096][1024]), z=1 -> K, z=2 -> V transposed
// per head: Vt[(b*16+h)*64 + d][s] via LDS transpose for coalesced writes.
__global__ __launch_bounds__(256) void qkv_gemm(
    const uint16_t* __restrict__ Xb,
    const uint16_t* __restrict__ WqT, const uint16_t* __restrict__ WkT,
    const uint16_t* __restrict__ WvT,
    const float* __restrict__ bq, const float* __restrict__ bk,
    const float* __restrict__ bv,
    uint16_t* __restrict__ Qo, uint16_t* __restrict__ Ko, uint16_t* __restrict__ Vt) {
  __shared__ __align__(16) uint16_t smem[17408];   // As/Bs dbuf (32KB) aliased with T
  uint16_t* As = smem;                             // [2][128][32]
  uint16_t* Bs = smem + 8192;                      // [2][128][32]
  uint16_t* T  = smem;                             // [128 ch][136] transpose buf (z==2)
  const int z = blockIdx.z;
  const uint16_t* BT  = (z == 0) ? WqT : (z == 1) ? WkT : WvT;
  const float*   bias = (z == 0) ? bq  : (z == 1) ? bk  : bv;
  const int m0 = blockIdx.x * 128, n0 = blockIdx.y * 128;
  const int lane = threadIdx.x & 63, qi = lane & 15, g = lane >> 4;
  const int wm = (threadIdx.x >> 7) & 1, wn = (threadIdx.x >> 6) & 1;
  const float l2e = 1.4426950408889634f * 0.125f;  // log2(e)/sqrt(dk), folded into Q

  const f32x4 ZERO = {0.f, 0.f, 0.f, 0.f};
  f32x4 acc[4][4];
#pragma unroll
  for (int i = 0; i < 4; i++)
#pragma unroll
    for (int j = 0; j < 4; j++) acc[i][j] = ZERO;

  if (z == 2) {
    gemm_core<false>(Xb, BT, As, Bs, m0, n0, 0, D_MODEL, acc);
    __syncthreads();  // all waves done with As/Bs before T overwrite
    // C: col = channel (qi), rows = 4 consecutive tokens -> T[ch][token] (stride 136)
#pragma unroll
    for (int i = 0; i < 4; i++) {
      int tok = wm * 64 + i * 16 + g * 4;
#pragma unroll
      for (int j = 0; j < 4; j++) {
        int ch = wn * 64 + j * 16 + qi;
        float bb = bias[n0 + ch];
        uint32_t lo = (uint32_t)f2b(acc[i][j][0] + bb) | ((uint32_t)f2b(acc[i][j][1] + bb) << 16);
        uint32_t hi = (uint32_t)f2b(acc[i][j][2] + bb) | ((uint32_t)f2b(acc[i][j][3] + bb) << 16);
        uint2 pk = {lo, hi};
        *(uint2*)(T + ch * 136 + tok) = pk;
      }
    }
    __syncthreads();
    // coalesced write-out: thread -> (channel, s-half), 128B contiguous per thread
    {
      int ch = threadIdx.x >> 1, sh = threadIdx.x & 1;
      const uint16_t* src = T + ch * 136 + sh * 64;
      int bidx = m0 >> 11;
      uint16_t* dst = Vt + ((size_t)(bidx * D_MODEL + n0 + ch)) * SEQ + (m0 & 2047) + sh * 64;
#pragma unroll
      for (int u = 0; u < 8; u++)
        *(uint4*)(dst + u * 8) = *(const uint4*)(src + u * 8);
    }
  } else {
    gemm_core<true>(Xb, BT, As, Bs, m0, n0, 0, D_MODEL, acc);
    // swapped C: col = token (qi), rows = 4 consecutive channels -> one uint2/tile
    uint16_t* O = z ? Ko : Qo;
    const float osc = (z == 0) ? l2e : 1.0f;
#pragma unroll
    for (int i = 0; i < 4; i++) {
      size_t tok = m0 + wm * 64 + i * 16 + qi;
#pragma unroll
      for (int j = 0; j < 4; j++) {
        int ch = n0 + wn * 64 + j * 16 + g * 4;
        float4 bb = *(const float4*)(bias + ch);
        uint32_t lo = (uint32_t)f2b((acc[i][j][0] + bb.x) * osc) |
                      ((uint32_t)f2b((acc[i][j][1] + bb.y) * osc) << 16);
        uint32_t hi = (uint32_t)f2b((acc[i][j][2] + bb.z) * osc) |
                      ((uint32_t)f2b((acc[i][j][3] + bb.w) * osc) << 16);
        uint2 pk = {lo, hi};
        *(uint2*)(O + tok * D_MODEL + ch) = pk;
      }
    }
  }
}

// ---------------- output projection (fp32 out, coalesced float4 stores) ----------------
__global__ __launch_bounds__(256) void oproj_gemm(
    const uint16_t* __restrict__ Ab, const uint16_t* __restrict__ WoT,
    const float* __restrict__ bo, float* __restrict__ out) {
  __shared__ __align__(16) uint16_t As[8192];   // [2][128][32]
  __shared__ __align__(16) uint16_t Bs[8192];
  const int m0 = blockIdx.x * 128, n0 = blockIdx.y * 128;
  const f32x4 ZERO = {0.f, 0.f, 0.f, 0.f};
  f32x4 acc[4][4];
#pragma unroll
  for (int i = 0; i < 4; i++)
#pragma unroll
    for (int j = 0; j < 4; j++) acc[i][j] = ZERO;

  gemm_core<true>(Ab, WoT, As, Bs, m0, n0, 0, D_MODEL, acc);

  const int lane = threadIdx.x & 63, qi = lane & 15, g = lane >> 4;
  const int wm = (threadIdx.x >> 7) & 1, wn = (threadIdx.x >> 6) & 1;
  // swapped C: col = token (qi), rows = 4 consecutive channels -> float4 store
#pragma unroll
  for (int i = 0; i < 4; i++) {
    size_t tok = m0 + wm * 64 + i * 16 + qi;
#pragma unroll
    for (int j = 0; j < 4; j++) {
      int ch = n0 + wn * 64 + j * 16 + g * 4;
      float4 bb = *(const float4*)(bo + ch);
      float4 o = {acc[i][j][0] + bb.x, acc[i][j][1] + bb.y,
                  acc[i][j][2] + bb.z, acc[i][j][3] + bb.w};
      *(float4*)(out + tok * D_MODEL + ch) = o;
    }
  }
}

// ---------------- flash attention, static softmax, transposed MFMA ----------------
// Q pre-scaled by log2(e)/sqrt(dk) -> P = exp2(sacc) directly. P packed to bf16 via
// v_perm (truncation); l sums the full-precision p (RTZ norm bias ~2e-4, in budget).
// XOR-swizzled K/V/Q staging keeps b128 fragment reads ~conflict-free.
__global__ __launch_bounds__(256) void attn_fwd(
    const uint16_t* __restrict__ Q, const uint16_t* __restrict__ K,
    const uint16_t* __restrict__ Vt, uint16_t* __restrict__ O) {
  __shared__ __align__(16) uint16_t sm[25600];   // 51200 B
  uint16_t* Q0 = sm;            // [128][32] d 0..31
  uint16_t* Q1 = sm + 4096;     // [128][32] d 32..63
  uint16_t* K0 = sm + 8192;     // [64][32]
  uint16_t* K1 = sm + 10240;
  uint16_t* V0 = sm + 12288;    // [64 d][32 kk]
  uint16_t* V1 = sm + 14336;
  uint16_t* Ps = sm + 16384;    // [128 q][72]

  const int t = threadIdx.x, lane = t & 63, w = t >> 6;
  const int g = lane >> 4, qi = lane & 15;
  const int wbase = t & 192;
  const int sc = (t & 3) ^ ((t >> 3) & 3);       // swizzled staging chunk
  const int rch = (g ^ ((qi >> 1) & 3)) * 8;     // swizzled read chunk (elems)
  const int q0 = blockIdx.x * 128;
  const int bh = blockIdx.y, b = bh >> 4, h = bh & 15;
  const uint16_t* Qp = Q + (size_t)b * SEQ * D_MODEL + h * DKH;
  const uint16_t* Kp = K + (size_t)b * SEQ * D_MODEL + h * DKH;
  const uint16_t* Vp = Vt + (size_t)bh * DKH * SEQ;

  // stage Q tile once: 128 rows x 64 d, two stride-32 halves
#pragma unroll
  for (int hs = 0; hs < 2; hs++) {
    uint16_t* Qs = hs ? Q1 : Q0;
#pragma unroll
    for (int j = 0; j < 2; j++) {
      int row = j * 64 + (t >> 2);
      gl2lds16(Qp + (size_t)(q0 + row) * D_MODEL + hs * 32 + sc * 8,
               Qs + (j * 256 + wbase) * 8);
    }
  }

  float lsum[2] = {0.f, 0.f};
  const f32x4 ZERO = {0.f, 0.f, 0.f, 0.f};
  f32x4 oaccT[4][2];   // [d-tile][q-tile]
#pragma unroll
  for (int d = 0; d < 4; d++)
#pragma unroll
    for (int i = 0; i < 2; i++) oaccT[d][i] = ZERO;

  for (int kt = 0; kt < SEQ / 64; kt++) {
    __syncthreads();
    {
      int row = t >> 2, c8 = sc * 8;
      const uint16_t* Kr = Kp + (size_t)(kt * 64 + row) * D_MODEL;
      const uint16_t* Vr = Vp + (size_t)row * SEQ + kt * 64;
      gl2lds16(Kr + c8,       K0 + wbase * 8);
      gl2lds16(Kr + 32 + c8,  K1 + wbase * 8);
      gl2lds16(Vr + c8,       V0 + wbase * 8);
      gl2lds16(Vr + 32 + c8,  V1 + wbase * 8);
    }
    __syncthreads();

    // S^T[kk][q] = K Q^T (Q pre-scaled -> log2-domain scores)
    f32x4 sacc[4][2];
#pragma unroll
    for (int j = 0; j < 4; j++)
#pragma unroll
      for (int i = 0; i < 2; i++) sacc[j][i] = ZERO;
#pragma unroll
    for (int ks = 0; ks < 2; ks++) {
      const uint16_t* Ksb = ks ? K1 : K0;
      const uint16_t* Qsb = ks ? Q1 : Q0;
      bf16x8 kf[4], qf[2];
#pragma unroll
      for (int j = 0; j < 4; j++)
        kf[j] = *(const bf16x8*)(Ksb + (j * 16 + qi) * 32 + rch);
#pragma unroll
      for (int i = 0; i < 2; i++)
        qf[i] = *(const bf16x8*)(Qsb + (w * 32 + i * 16 + qi) * 32 + rch);
#pragma unroll
      for (int j = 0; j < 4; j++)
#pragma unroll
        for (int i = 0; i < 2; i++)
          sacc[j][i] = __builtin_amdgcn_mfma_f32_16x16x32_bf16(kf[j], qf[i], sacc[j][i], 0, 0, 0);
    }

    // P = exp2(s); pack to bf16 via v_perm (RTZ); l sums full-precision p
#pragma unroll
    for (int i = 0; i < 2; i++) {
      uint16_t* Pr = Ps + (w * 32 + i * 16 + qi) * 72;
#pragma unroll
      for (int j = 0; j < 4; j++) {
        float p0 = __builtin_amdgcn_exp2f(sacc[j][i][0]);
        float p1 = __builtin_amdgcn_exp2f(sacc[j][i][1]);
        float p2 = __builtin_amdgcn_exp2f(sacc[j][i][2]);
        float p3 = __builtin_amdgcn_exp2f(sacc[j][i][3]);
        lsum[i] += (p0 + p1) + (p2 + p3);
        uint2 pk = {__builtin_amdgcn_perm(__builtin_bit_cast(uint32_t, p1),
                                          __builtin_bit_cast(uint32_t, p0), 0x07060302u),
                    __builtin_amdgcn_perm(__builtin_bit_cast(uint32_t, p3),
                                          __builtin_bit_cast(uint32_t, p2), 0x07060302u)};
        *(uint2*)(Pr + j * 16 + g * 4) = pk;
      }
    }
    __syncthreads();

    // O^T[d][q] += V^T P^T
#pragma unroll
    for (int ks = 0; ks < 2; ks++) {
      const uint16_t* Vsb = ks ? V1 : V0;
      bf16x8 vf[4], pf[2];
#pragma unroll
      for (int d = 0; d < 4; d++)
        vf[d] = *(const bf16x8*)(Vsb + (d * 16 + qi) * 32 + rch);
#pragma unroll
      for (int i = 0; i < 2; i++)
        pf[i] = *(const bf16x8*)(Ps + (w * 32 + i * 16 + qi) * 72 + ks * 32 + g * 8);
#pragma unroll
      for (int d = 0; d < 4; d++)
#pragma unroll
        for (int i = 0; i < 2; i++)
          oaccT[d][i] = __builtin_amdgcn_mfma_f32_16x16x32_bf16(vf[d], pf[i], oaccT[d][i], 0, 0, 0);
    }
  }

  // final l reduction over the 4 lane-groups holding the same q
#pragma unroll
  for (int i = 0; i < 2; i++) {
    lsum[i] += __shfl_xor(lsum[i], 16, 64);
    lsum[i] += __shfl_xor(lsum[i], 32, 64);
  }
  float rl[2] = {1.f / lsum[0], 1.f / lsum[1]};

  // epilogue: O[q][h*64+d] = O^T/l (RNE), 4 consecutive d per 8B store
#pragma unroll
  for (int i = 0; i < 2; i++) {
    size_t row = (size_t)b * SEQ + q0 + w * 32 + i * 16 + qi;
#pragma unroll
    for (int d = 0; d < 4; d++) {
      uint32_t lo = (uint32_t)f2b(oaccT[d][i][0] * rl[i]) |
                    ((uint32_t)f2b(oaccT[d][i][1] * rl[i]) << 16);
      uint32_t hi = (uint32_t)f2b(oaccT[d][i][2] * rl[i]) |
                    ((uint32_t)f2b(oaccT[d][i][3] * rl[i]) << 16);
      uint2 pk = {lo, hi};
      *(uint2*)(O + row * D_MODEL + h * DKH + d * 16 + g * 4) = pk;
    }
  }
}

extern "C" void kernel_launch(void* const* d_in, const int* in_sizes, int n_in,
                              void* d_out, int out_size, void* d_ws, size_t ws_size,
                              hipStream_t stream) {
  (void)in_sizes; (void)n_in; (void)out_size; (void)ws_size;
  const float* X  = (const float*)d_in[0];
  const float* Wq = (const float*)d_in[1];
  const float* bq = (const float*)d_in[2];
  const float* Wk = (const float*)d_in[3];
  const float* bk = (const float*)d_in[4];
  const float* Wv = (const float*)d_in[5];
  const float* bv = (const float*)d_in[6];
  const float* Wo = (const float*)d_in[7];
  const float* bo = (const float*)d_in[8];
  float* out = (float*)d_out;

  char* p = (char*)d_ws;
  uint16_t* Xb  = (uint16_t*)p; p += (size_t)M_TOK * D_MODEL * 2;
  uint16_t* WqT = (uint16_t*)p; p += (size_t)D_MODEL * D_MODEL * 2;
  uint16_t* WkT = (uint16_t*)p; p += (size_t)D_MODEL * D_MODEL * 2;
  uint16_t* WvT = (uint16_t*)p; p += (size_t)D_MODEL * D_MODEL * 2;
  uint16_t* WoT = (uint16_t*)p; p += (size_t)D_MODEL * D_MODEL * 2;
  uint16_t* Qw  = (uint16_t*)p; p += (size_t)M_TOK * D_MODEL * 2;
  uint16_t* Kw  = (uint16_t*)p; p += (size_t)M_TOK * D_MODEL * 2;
  uint16_t* Vt  = (uint16_t*)p; p += (size_t)M_TOK * D_MODEL * 2;
  uint16_t* Ob  = (uint16_t*)p; p += (size_t)M_TOK * D_MODEL * 2;

  convx<<<(M_TOK * D_MODEL) / (256 * 8), 256, 0, stream>>>(X, Xb);
  wtrans<<<dim3(32, 32, 4), dim3(32, 32), 0, stream>>>(Wq, Wk, Wv, Wo, WqT, WkT, WvT, WoT);
  qkv_gemm<<<dim3(32, 8, 3), 256, 0, stream>>>(Xb, WqT, WkT, WvT, bq, bk, bv, Qw, Kw, Vt);
  attn_fwd<<<dim3(SEQ / 128, BATCH * NH), 256, 0, stream>>>(Qw, Kw, Vt, Ob);
  oproj_gemm<<<dim3(32, 8), 256, 0, stream>>>(Ob, WoT, bo, out);
}

// Round 5
// 204.190 us; speedup vs baseline: 1.1804x; 1.0203x over previous
//
#include <hip/hip_runtime.h>
#include <stdint.h>

#define D_MODEL 1024
#define NH      16
#define DKH     64
#define BATCH   2
#define SEQ     2048
#define M_TOK   (BATCH*SEQ)   // 4096

typedef __attribute__((ext_vector_type(8))) short bf16x8;   // 8 bf16 = 4 VGPRs
typedef __attribute__((ext_vector_type(4))) float f32x4;    // MFMA C/D

// fp32 -> bf16, round-to-nearest-even
__device__ __forceinline__ uint16_t f2b(float f) {
  uint32_t u = __builtin_bit_cast(uint32_t, f);
  return (uint16_t)((u + 0x7FFFu + ((u >> 16) & 1u)) >> 16);
}

// async global->LDS, 16B per lane. HW writes LDS at wave-uniform base + lane*16.
__device__ __forceinline__ void gl2lds16(const uint16_t* g, uint16_t* l) {
  __builtin_amdgcn_global_load_lds(
      (const __attribute__((address_space(1))) void*)g,
      (__attribute__((address_space(3))) void*)l, 16, 0, 0);
}

// ---------------- convert X to bf16 ----------------
__global__ void convx(const float* __restrict__ X, uint16_t* __restrict__ Xb) {
  int i = (blockIdx.x * 256 + threadIdx.x) * 8;
  float4 a = *(const float4*)(X + i);
  float4 b = *(const float4*)(X + i + 4);
  uint16_t tmp[8] = {f2b(a.x), f2b(a.y), f2b(a.z), f2b(a.w),
                     f2b(b.x), f2b(b.y), f2b(b.z), f2b(b.w)};
  *(uint4*)(Xb + i) = *(const uint4*)tmp;
}

// ------------- transpose + convert W ([K][N] fp32 -> [N][K] bf16) -------------
__global__ void wtrans(const float* __restrict__ W0, const float* __restrict__ W1,
                       const float* __restrict__ W2, const float* __restrict__ W3,
                       uint16_t* __restrict__ T0, uint16_t* __restrict__ T1,
                       uint16_t* __restrict__ T2, uint16_t* __restrict__ T3) {
  __shared__ float tile[32][33];
  int z = blockIdx.z;
  const float* W = (z == 0) ? W0 : (z == 1) ? W1 : (z == 2) ? W2 : W3;
  uint16_t*    T = (z == 0) ? T0 : (z == 1) ? T1 : (z == 2) ? T2 : T3;
  int k0 = blockIdx.x * 32, n0 = blockIdx.y * 32;
  int tx = threadIdx.x, ty = threadIdx.y;
  tile[ty][tx] = W[(size_t)(k0 + ty) * D_MODEL + n0 + tx];
  __syncthreads();
  T[(size_t)(n0 + ty) * D_MODEL + k0 + tx] = f2b(tile[tx][ty]);
}

// ------ 128x128 bf16 MFMA GEMM core: double-buffered LDS, 1 barrier/K-step ------
template <bool SWAP>
__device__ __forceinline__ void gemm_core(const uint16_t* __restrict__ A,
                                          const uint16_t* __restrict__ BT,
                                          uint16_t* As, uint16_t* Bs,
                                          int m0, int n0, int kBeg, int kEnd,
                                          f32x4 (&acc)[4][4]) {
  const int t    = threadIdx.x;
  const int lane = t & 63;
  const int qi   = lane & 15, g = lane >> 4;
  const int wm   = (t >> 7) & 1;
  const int wn   = (t >> 6) & 1;
  const int srow = t >> 2;                       // staging row 0..63
  const int sc   = (t & 3) ^ ((t >> 3) & 3);     // swizzled global chunk
  const int wbase = t & 192;
  const int rch  = (g ^ ((qi >> 1) & 3)) * 8;    // swizzled read chunk (elems)

  const uint16_t* Ag = A  + (size_t)(m0 + srow) * D_MODEL + sc * 8;
  const uint16_t* Bg = BT + (size_t)(n0 + srow) * D_MODEL + sc * 8;

#pragma unroll
  for (int j = 0; j < 2; j++) {
    gl2lds16(Ag + (size_t)j * 64 * D_MODEL + kBeg, As + (j * 256 + wbase) * 8);
    gl2lds16(Bg + (size_t)j * 64 * D_MODEL + kBeg, Bs + (j * 256 + wbase) * 8);
  }

  int cur = 0;
  for (int k0 = kBeg; k0 < kEnd; k0 += 32) {
    __syncthreads();   // publishes buf[cur] (vmcnt drain) + reads of buf[cur^1] done
    int kn = k0 + 32;
    if (kn < kEnd) {
      int nb = (cur ^ 1) * 4096;
#pragma unroll
      for (int j = 0; j < 2; j++) {
        gl2lds16(Ag + (size_t)j * 64 * D_MODEL + kn, As + nb + (j * 256 + wbase) * 8);
        gl2lds16(Bg + (size_t)j * 64 * D_MODEL + kn, Bs + nb + (j * 256 + wbase) * 8);
      }
    }
    const uint16_t* Ab = As + cur * 4096;
    const uint16_t* Bb = Bs + cur * 4096;
    bf16x8 af[4], bf[4];
#pragma unroll
    for (int i = 0; i < 4; i++) {
      af[i] = *(const bf16x8*)(Ab + (wm * 64 + i * 16 + qi) * 32 + rch);
      bf[i] = *(const bf16x8*)(Bb + (wn * 64 + i * 16 + qi) * 32 + rch);
    }
#pragma unroll
    for (int i = 0; i < 4; i++)
#pragma unroll
      for (int j = 0; j < 4; j++)
        acc[i][j] = SWAP
          ? __builtin_amdgcn_mfma_f32_16x16x32_bf16(bf[j], af[i], acc[i][j], 0, 0, 0)
          : __builtin_amdgcn_mfma_f32_16x16x32_bf16(af[i], bf[j], acc[i][j], 0, 0, 0);
    cur ^= 1;
  }
}

// ---------------- fused QKV projection ----------------
__global__ __launch_bounds__(256) void qkv_gemm(
    const uint16_t* __restrict__ Xb,
    const uint16_t* __restrict__ WqT, const uint16_t* __restrict__ WkT,
    const uint16_t* __restrict__ WvT,
    const float* __restrict__ bq, const float* __restrict__ bk,
    const float* __restrict__ bv,
    uint16_t* __restrict__ Qo, uint16_t* __restrict__ Ko, uint16_t* __restrict__ Vt) {
  __shared__ __align__(16) uint16_t smem[17408];   // As/Bs dbuf (32KB) aliased with T
  uint16_t* As = smem;                             // [2][128][32]
  uint16_t* Bs = smem + 8192;                      // [2][128][32]
  uint16_t* T  = smem;                             // [128 ch][136] transpose buf (z==2)
  const int z = blockIdx.z;
  const uint16_t* BT  = (z == 0) ? WqT : (z == 1) ? WkT : WvT;
  const float*   bias = (z == 0) ? bq  : (z == 1) ? bk  : bv;
  const int m0 = blockIdx.x * 128, n0 = blockIdx.y * 128;
  const int lane = threadIdx.x & 63, qi = lane & 15, g = lane >> 4;
  const int wm = (threadIdx.x >> 7) & 1, wn = (threadIdx.x >> 6) & 1;
  const float l2e = 1.4426950408889634f * 0.125f;  // log2(e)/sqrt(dk), folded into Q

  const f32x4 ZERO = {0.f, 0.f, 0.f, 0.f};
  f32x4 acc[4][4];
#pragma unroll
  for (int i = 0; i < 4; i++)
#pragma unroll
    for (int j = 0; j < 4; j++) acc[i][j] = ZERO;

  if (z == 2) {
    gemm_core<false>(Xb, BT, As, Bs, m0, n0, 0, D_MODEL, acc);
    __syncthreads();  // all waves done with As/Bs before T overwrite
#pragma unroll
    for (int i = 0; i < 4; i++) {
      int tok = wm * 64 + i * 16 + g * 4;
#pragma unroll
      for (int j = 0; j < 4; j++) {
        int ch = wn * 64 + j * 16 + qi;
        float bb = bias[n0 + ch];
        uint32_t lo = (uint32_t)f2b(acc[i][j][0] + bb) | ((uint32_t)f2b(acc[i][j][1] + bb) << 16);
        uint32_t hi = (uint32_t)f2b(acc[i][j][2] + bb) | ((uint32_t)f2b(acc[i][j][3] + bb) << 16);
        uint2 pk = {lo, hi};
        *(uint2*)(T + ch * 136 + tok) = pk;
      }
    }
    __syncthreads();
    {
      int ch = threadIdx.x >> 1, sh = threadIdx.x & 1;
      const uint16_t* src = T + ch * 136 + sh * 64;
      int bidx = m0 >> 11;
      uint16_t* dst = Vt + ((size_t)(bidx * D_MODEL + n0 + ch)) * SEQ + (m0 & 2047) + sh * 64;
#pragma unroll
      for (int u = 0; u < 8; u++)
        *(uint4*)(dst + u * 8) = *(const uint4*)(src + u * 8);
    }
  } else {
    gemm_core<true>(Xb, BT, As, Bs, m0, n0, 0, D_MODEL, acc);
    uint16_t* O = z ? Ko : Qo;
    const float osc = (z == 0) ? l2e : 1.0f;
#pragma unroll
    for (int i = 0; i < 4; i++) {
      size_t tok = m0 + wm * 64 + i * 16 + qi;
#pragma unroll
      for (int j = 0; j < 4; j++) {
        int ch = n0 + wn * 64 + j * 16 + g * 4;
        float4 bb = *(const float4*)(bias + ch);
        uint32_t lo = (uint32_t)f2b((acc[i][j][0] + bb.x) * osc) |
                      ((uint32_t)f2b((acc[i][j][1] + bb.y) * osc) << 16);
        uint32_t hi = (uint32_t)f2b((acc[i][j][2] + bb.z) * osc) |
                      ((uint32_t)f2b((acc[i][j][3] + bb.w) * osc) << 16);
        uint2 pk = {lo, hi};
        *(uint2*)(O + tok * D_MODEL + ch) = pk;
      }
    }
  }
}

// -------- output projection: 128x64 tiles (512 blocks = 2/CU), dbuf, fp32 out --------
__global__ __launch_bounds__(256) void oproj_gemm(
    const uint16_t* __restrict__ Ab, const uint16_t* __restrict__ WoT,
    const float* __restrict__ bo, float* __restrict__ out) {
  __shared__ __align__(16) uint16_t As[8192];   // [2][128][32]
  __shared__ __align__(16) uint16_t Bs[4096];   // [2][64][32]
  const int t = threadIdx.x;
  const int lane = t & 63, qi = lane & 15, g = lane >> 4;
  const int wm = (t >> 7) & 1;                  // token-half (64 rows)
  const int wn = (t >> 6) & 1;                  // channel-half (32 cols)
  const int srow = t >> 2;
  const int sc = (t & 3) ^ ((t >> 3) & 3);
  const int wbase = t & 192;
  const int rch = (g ^ ((qi >> 1) & 3)) * 8;
  const int m0 = blockIdx.x * 128, n0 = blockIdx.y * 64;

  const uint16_t* Ag = Ab  + (size_t)(m0 + srow) * D_MODEL + sc * 8;
  const uint16_t* Bg = WoT + (size_t)(n0 + srow) * D_MODEL + sc * 8;

  const f32x4 ZERO = {0.f, 0.f, 0.f, 0.f};
  f32x4 acc[4][2];   // [token-tile][ch-tile], SWAP layout (col=token, rows=channels)
#pragma unroll
  for (int i = 0; i < 4; i++)
#pragma unroll
    for (int j = 0; j < 2; j++) acc[i][j] = ZERO;

  gl2lds16(Ag, As + wbase * 8);
  gl2lds16(Ag + (size_t)64 * D_MODEL, As + (256 + wbase) * 8);
  gl2lds16(Bg, Bs + wbase * 8);

  int cur = 0;
  for (int k0 = 0; k0 < D_MODEL; k0 += 32) {
    __syncthreads();
    int kn = k0 + 32;
    if (kn < D_MODEL) {
      int nbA = (cur ^ 1) * 4096, nbB = (cur ^ 1) * 2048;
      gl2lds16(Ag + kn, As + nbA + wbase * 8);
      gl2lds16(Ag + (size_t)64 * D_MODEL + kn, As + nbA + (256 + wbase) * 8);
      gl2lds16(Bg + kn, Bs + nbB + wbase * 8);
    }
    const uint16_t* Abuf = As + cur * 4096;
    const uint16_t* Bbuf = Bs + cur * 2048;
    bf16x8 af[4], bf[2];
#pragma unroll
    for (int i = 0; i < 4; i++)
      af[i] = *(const bf16x8*)(Abuf + (wm * 64 + i * 16 + qi) * 32 + rch);
#pragma unroll
    for (int j = 0; j < 2; j++)
      bf[j] = *(const bf16x8*)(Bbuf + (wn * 32 + j * 16 + qi) * 32 + rch);
#pragma unroll
    for (int i = 0; i < 4; i++)
#pragma unroll
      for (int j = 0; j < 2; j++)
        acc[i][j] = __builtin_amdgcn_mfma_f32_16x16x32_bf16(bf[j], af[i], acc[i][j], 0, 0, 0);
    cur ^= 1;
  }

#pragma unroll
  for (int i = 0; i < 4; i++) {
    size_t tok = m0 + wm * 64 + i * 16 + qi;
#pragma unroll
    for (int j = 0; j < 2; j++) {
      int ch = n0 + wn * 32 + j * 16 + g * 4;
      float4 bb = *(const float4*)(bo + ch);
      float4 o = {acc[i][j][0] + bb.x, acc[i][j][1] + bb.y,
                  acc[i][j][2] + bb.z, acc[i][j][3] + bb.w};
      *(float4*)(out + tok * D_MODEL + ch) = o;
    }
  }
}

// ------- flash attention: K/V double-buffered, 1 barrier/iter, Q frags in regs -------
// Q pre-scaled by log2(e)/sqrt(dk) -> P = exp2(s). P round-trip through Ps is
// WAVE-LOCAL (wave w writes and reads only q-rows w*32..+31), so no barrier between
// P-write and PV — compiler's lgkmcnt ordering suffices. One __syncthreads per K-tile
// publishes the prefetched K/V buffer (in flight for a full compute phase).
__global__ __launch_bounds__(256) void attn_fwd(
    const uint16_t* __restrict__ Q, const uint16_t* __restrict__ K,
    const uint16_t* __restrict__ Vt, uint16_t* __restrict__ O) {
  __shared__ __align__(16) uint16_t sm[33792];   // 67584 B -> 2 blocks/CU
  // Q: [0,8192) two stride-32 halves; K bufs: 8192 + buf*4096 (lo/hi 2048);
  // V bufs: 16384 + buf*4096; Ps: [24576, 33792) = [128 q][72]
  uint16_t* Ps = sm + 24576;

  const int t = threadIdx.x, lane = t & 63, w = t >> 6;
  const int g = lane >> 4, qi = lane & 15;
  const int wbase = t & 192;
  const int sc = (t & 3) ^ ((t >> 3) & 3);
  const int rch = (g ^ ((qi >> 1) & 3)) * 8;
  const int q0 = blockIdx.x * 128;
  const int bh = blockIdx.y, b = bh >> 4, h = bh & 15;
  const uint16_t* Qp = Q + (size_t)b * SEQ * D_MODEL + h * DKH;
  const uint16_t* Kp = K + (size_t)b * SEQ * D_MODEL + h * DKH;
  const uint16_t* Vp = Vt + (size_t)bh * DKH * SEQ;

  const int srow = t >> 2, c8 = sc * 8;

  // stage Q (once) + K/V tile 0 into buf 0
#pragma unroll
  for (int hs = 0; hs < 2; hs++)
#pragma unroll
    for (int j = 0; j < 2; j++)
      gl2lds16(Qp + (size_t)(q0 + j * 64 + srow) * D_MODEL + hs * 32 + c8,
               sm + hs * 4096 + (j * 256 + wbase) * 8);
  {
    const uint16_t* Kr = Kp + (size_t)srow * D_MODEL;
    const uint16_t* Vr = Vp + (size_t)srow * SEQ;
    gl2lds16(Kr + c8,      sm + 8192 + wbase * 8);
    gl2lds16(Kr + 32 + c8, sm + 8192 + 2048 + wbase * 8);
    gl2lds16(Vr + c8,      sm + 16384 + wbase * 8);
    gl2lds16(Vr + 32 + c8, sm + 16384 + 2048 + wbase * 8);
  }
  __syncthreads();   // Q + buf0 visible

  // hoist Q fragments into registers (reused all 32 iterations)
  bf16x8 qf[2][2];
#pragma unroll
  for (int ks = 0; ks < 2; ks++)
#pragma unroll
    for (int i = 0; i < 2; i++)
      qf[ks][i] = *(const bf16x8*)(sm + ks * 4096 + (w * 32 + i * 16 + qi) * 32 + rch);

  float lsum[2] = {0.f, 0.f};
  const f32x4 ZERO = {0.f, 0.f, 0.f, 0.f};
  f32x4 oaccT[4][2];   // [d-tile][q-tile]
#pragma unroll
  for (int d = 0; d < 4; d++)
#pragma unroll
    for (int i = 0; i < 2; i++) oaccT[d][i] = ZERO;

  int cur = 0;
  for (int kt = 0; kt < SEQ / 64; kt++) {
    // prefetch next K/V tile into the other buffer (in flight across this compute)
    if (kt + 1 < SEQ / 64) {
      int nb = (cur ^ 1) * 4096;
      const uint16_t* Kr = Kp + (size_t)((kt + 1) * 64 + srow) * D_MODEL;
      const uint16_t* Vr = Vp + (size_t)srow * SEQ + (kt + 1) * 64;
      gl2lds16(Kr + c8,      sm + 8192 + nb + wbase * 8);
      gl2lds16(Kr + 32 + c8, sm + 8192 + nb + 2048 + wbase * 8);
      gl2lds16(Vr + c8,      sm + 16384 + nb + wbase * 8);
      gl2lds16(Vr + 32 + c8, sm + 16384 + nb + 2048 + wbase * 8);
    }
    const uint16_t* Kb = sm + 8192 + cur * 4096;
    const uint16_t* Vb = sm + 16384 + cur * 4096;

    // S^T[kk][q] = K Q^T
    f32x4 sacc[4][2];
#pragma unroll
    for (int j = 0; j < 4; j++)
#pragma unroll
      for (int i = 0; i < 2; i++) sacc[j][i] = ZERO;
#pragma unroll
    for (int ks = 0; ks < 2; ks++) {
      const uint16_t* Ksb = Kb + ks * 2048;
      bf16x8 kf[4];
#pragma unroll
      for (int j = 0; j < 4; j++)
        kf[j] = *(const bf16x8*)(Ksb + (j * 16 + qi) * 32 + rch);
#pragma unroll
      for (int j = 0; j < 4; j++)
#pragma unroll
        for (int i = 0; i < 2; i++)
          sacc[j][i] = __builtin_amdgcn_mfma_f32_16x16x32_bf16(kf[j], qf[ks][i], sacc[j][i], 0, 0, 0);
    }

    // P = exp2(s); pack bf16 (RTZ via v_perm); l sums full-precision p
#pragma unroll
    for (int i = 0; i < 2; i++) {
      uint16_t* Pr = Ps + (w * 32 + i * 16 + qi) * 72;
#pragma unroll
      for (int j = 0; j < 4; j++) {
        float p0 = __builtin_amdgcn_exp2f(sacc[j][i][0]);
        float p1 = __builtin_amdgcn_exp2f(sacc[j][i][1]);
        float p2 = __builtin_amdgcn_exp2f(sacc[j][i][2]);
        float p3 = __builtin_amdgcn_exp2f(sacc[j][i][3]);
        lsum[i] += (p0 + p1) + (p2 + p3);
        uint2 pk = {__builtin_amdgcn_perm(__builtin_bit_cast(uint32_t, p1),
                                          __builtin_bit_cast(uint32_t, p0), 0x07060302u),
                    __builtin_amdgcn_perm(__builtin_bit_cast(uint32_t, p3),
                                          __builtin_bit_cast(uint32_t, p2), 0x07060302u)};
        *(uint2*)(Pr + j * 16 + g * 4) = pk;
      }
    }
    // no barrier: P round-trip is wave-local (same q-rows written & read by wave w)

    // O^T[d][q] += V^T P^T
#pragma unroll
    for (int ks = 0; ks < 2; ks++) {
      const uint16_t* Vsb = Vb + ks * 2048;
      bf16x8 vf[4], pf[2];
#pragma unroll
      for (int d = 0; d < 4; d++)
        vf[d] = *(const bf16x8*)(Vsb + (d * 16 + qi) * 32 + rch);
#pragma unroll
      for (int i = 0; i < 2; i++)
        pf[i] = *(const bf16x8*)(Ps + (w * 32 + i * 16 + qi) * 72 + ks * 32 + g * 8);
#pragma unroll
      for (int d = 0; d < 4; d++)
#pragma unroll
        for (int i = 0; i < 2; i++)
          oaccT[d][i] = __builtin_amdgcn_mfma_f32_16x16x32_bf16(vf[d], pf[i], oaccT[d][i], 0, 0, 0);
    }

    if (kt + 1 < SEQ / 64) __syncthreads();  // publish prefetched buffer; reads of cur done
    cur ^= 1;
  }

  // final l reduction over the 4 lane-groups holding the same q
#pragma unroll
  for (int i = 0; i < 2; i++) {
    lsum[i] += __shfl_xor(lsum[i], 16, 64);
    lsum[i] += __shfl_xor(lsum[i], 32, 64);
  }
  float rl[2] = {1.f / lsum[0], 1.f / lsum[1]};

  // epilogue: O[q][h*64+d] = O^T/l (RNE), 4 consecutive d per 8B store
#pragma unroll
  for (int i = 0; i < 2; i++) {
    size_t row = (size_t)b * SEQ + q0 + w * 32 + i * 16 + qi;
#pragma unroll
    for (int d = 0; d < 4; d++) {
      uint32_t lo = (uint32_t)f2b(oaccT[d][i][0] * rl[i]) |
                    ((uint32_t)f2b(oaccT[d][i][1] * rl[i]) << 16);
      uint32_t hi = (uint32_t)f2b(oaccT[d][i][2] * rl[i]) |
                    ((uint32_t)f2b(oaccT[d][i][3] * rl[i]) << 16);
      uint2 pk = {lo, hi};
      *(uint2*)(O + row * D_MODEL + h * DKH + d * 16 + g * 4) = pk;
    }
  }
}

extern "C" void kernel_launch(void* const* d_in, const int* in_sizes, int n_in,
                              void* d_out, int out_size, void* d_ws, size_t ws_size,
                              hipStream_t stream) {
  (void)in_sizes; (void)n_in; (void)out_size; (void)ws_size;
  const float* X  = (const float*)d_in[0];
  const float* Wq = (const float*)d_in[1];
  const float* bq = (const float*)d_in[2];
  const float* Wk = (const float*)d_in[3];
  const float* bk = (const float*)d_in[4];
  const float* Wv = (const float*)d_in[5];
  const float* bv = (const float*)d_in[6];
  const float* Wo = (const float*)d_in[7];
  const float* bo = (const float*)d_in[8];
  float* out = (float*)d_out;

  char* p = (char*)d_ws;
  uint16_t* Xb  = (uint16_t*)p; p += (size_t)M_TOK * D_MODEL * 2;
  uint16_t* WqT = (uint16_t*)p; p += (size_t)D_MODEL * D_MODEL * 2;
  uint16_t* WkT = (uint16_t*)p; p += (size_t)D_MODEL * D_MODEL * 2;
  uint16_t* WvT = (uint16_t*)p; p += (size_t)D_MODEL * D_MODEL * 2;
  uint16_t* WoT = (uint16_t*)p; p += (size_t)D_MODEL * D_MODEL * 2;
  uint16_t* Qw  = (uint16_t*)p; p += (size_t)M_TOK * D_MODEL * 2;
  uint16_t* Kw  = (uint16_t*)p; p += (size_t)M_TOK * D_MODEL * 2;
  uint16_t* Vt  = (uint16_t*)p; p += (size_t)M_TOK * D_MODEL * 2;
  uint16_t* Ob  = (uint16_t*)p; p += (size_t)M_TOK * D_MODEL * 2;

  convx<<<(M_TOK * D_MODEL) / (256 * 8), 256, 0, stream>>>(X, Xb);
  wtrans<<<dim3(32, 32, 4), dim3(32, 32), 0, stream>>>(Wq, Wk, Wv, Wo, WqT, WkT, WvT, WoT);
  qkv_gemm<<<dim3(32, 8, 3), 256, 0, stream>>>(Xb, WqT, WkT, WvT, bq, bk, bv, Qw, Kw, Vt);
  attn_fwd<<<dim3(SEQ / 128, BATCH * NH), 256, 0, stream>>>(Qw, Kw, Vt, Ob);
  oproj_gemm<<<dim3(32, 16), 256, 0, stream>>>(Ob, WoT, bo, out);
}

// Round 6
// 203.931 us; speedup vs baseline: 1.1819x; 1.0013x over previous
//
#include <hip/hip_runtime.h>
#include <stdint.h>

#define D_MODEL 1024
#define NH      16
#define DKH     64
#define BATCH   2
#define SEQ     2048
#define M_TOK   (BATCH*SEQ)   // 4096

typedef __attribute__((ext_vector_type(8))) short bf16x8;   // 8 bf16 = 4 VGPRs
typedef __attribute__((ext_vector_type(4))) float f32x4;    // MFMA C/D

// fp32 -> bf16, round-to-nearest-even
__device__ __forceinline__ uint16_t f2b(float f) {
  uint32_t u = __builtin_bit_cast(uint32_t, f);
  return (uint16_t)((u + 0x7FFFu + ((u >> 16) & 1u)) >> 16);
}

// async global->LDS, 16B per lane. HW writes LDS at wave-uniform base + lane*16.
__device__ __forceinline__ void gl2lds16(const uint16_t* g, uint16_t* l) {
  __builtin_amdgcn_global_load_lds(
      (const __attribute__((address_space(1))) void*)g,
      (__attribute__((address_space(3))) void*)l, 16, 0, 0);
}

// ---------------- convert X to bf16 ----------------
__global__ void convx(const float* __restrict__ X, uint16_t* __restrict__ Xb) {
  int i = (blockIdx.x * 256 + threadIdx.x) * 8;
  float4 a = *(const float4*)(X + i);
  float4 b = *(const float4*)(X + i + 4);
  uint16_t tmp[8] = {f2b(a.x), f2b(a.y), f2b(a.z), f2b(a.w),
                     f2b(b.x), f2b(b.y), f2b(b.z), f2b(b.w)};
  *(uint4*)(Xb + i) = *(const uint4*)tmp;
}

// ------------- transpose + convert W ([K][N] fp32 -> [N][K] bf16) -------------
__global__ void wtrans(const float* __restrict__ W0, const float* __restrict__ W1,
                       const float* __restrict__ W2, const float* __restrict__ W3,
                       uint16_t* __restrict__ T0, uint16_t* __restrict__ T1,
                       uint16_t* __restrict__ T2, uint16_t* __restrict__ T3) {
  __shared__ float tile[32][33];
  int z = blockIdx.z;
  const float* W = (z == 0) ? W0 : (z == 1) ? W1 : (z == 2) ? W2 : W3;
  uint16_t*    T = (z == 0) ? T0 : (z == 1) ? T1 : (z == 2) ? T2 : T3;
  int k0 = blockIdx.x * 32, n0 = blockIdx.y * 32;
  int tx = threadIdx.x, ty = threadIdx.y;
  tile[ty][tx] = W[(size_t)(k0 + ty) * D_MODEL + n0 + tx];
  __syncthreads();
  T[(size_t)(n0 + ty) * D_MODEL + k0 + tx] = f2b(tile[tx][ty]);
}

// ------ 128x128 bf16 MFMA GEMM core: double-buffered LDS, 1 barrier/K-step ------
template <bool SWAP>
__device__ __forceinline__ void gemm_core(const uint16_t* __restrict__ A,
                                          const uint16_t* __restrict__ BT,
                                          uint16_t* As, uint16_t* Bs,
                                          int m0, int n0, int kBeg, int kEnd,
                                          f32x4 (&acc)[4][4]) {
  const int t    = threadIdx.x;
  const int lane = t & 63;
  const int qi   = lane & 15, g = lane >> 4;
  const int wm   = (t >> 7) & 1;
  const int wn   = (t >> 6) & 1;
  const int srow = t >> 2;                       // staging row 0..63
  const int sc   = (t & 3) ^ ((t >> 3) & 3);     // swizzled global chunk
  const int wbase = t & 192;
  const int rch  = (g ^ ((qi >> 1) & 3)) * 8;    // swizzled read chunk (elems)

  const uint16_t* Ag = A  + (size_t)(m0 + srow) * D_MODEL + sc * 8;
  const uint16_t* Bg = BT + (size_t)(n0 + srow) * D_MODEL + sc * 8;

#pragma unroll
  for (int j = 0; j < 2; j++) {
    gl2lds16(Ag + (size_t)j * 64 * D_MODEL + kBeg, As + (j * 256 + wbase) * 8);
    gl2lds16(Bg + (size_t)j * 64 * D_MODEL + kBeg, Bs + (j * 256 + wbase) * 8);
  }

  int cur = 0;
  for (int k0 = kBeg; k0 < kEnd; k0 += 32) {
    __syncthreads();   // publishes buf[cur] (vmcnt drain) + reads of buf[cur^1] done
    int kn = k0 + 32;
    if (kn < kEnd) {
      int nb = (cur ^ 1) * 4096;
#pragma unroll
      for (int j = 0; j < 2; j++) {
        gl2lds16(Ag + (size_t)j * 64 * D_MODEL + kn, As + nb + (j * 256 + wbase) * 8);
        gl2lds16(Bg + (size_t)j * 64 * D_MODEL + kn, Bs + nb + (j * 256 + wbase) * 8);
      }
    }
    const uint16_t* Ab = As + cur * 4096;
    const uint16_t* Bb = Bs + cur * 4096;
    bf16x8 af[4], bf[4];
#pragma unroll
    for (int i = 0; i < 4; i++) {
      af[i] = *(const bf16x8*)(Ab + (wm * 64 + i * 16 + qi) * 32 + rch);
      bf[i] = *(const bf16x8*)(Bb + (wn * 64 + i * 16 + qi) * 32 + rch);
    }
#pragma unroll
    for (int i = 0; i < 4; i++)
#pragma unroll
      for (int j = 0; j < 4; j++)
        acc[i][j] = SWAP
          ? __builtin_amdgcn_mfma_f32_16x16x32_bf16(bf[j], af[i], acc[i][j], 0, 0, 0)
          : __builtin_amdgcn_mfma_f32_16x16x32_bf16(af[i], bf[j], acc[i][j], 0, 0, 0);
    cur ^= 1;
  }
}

// ---------------- fused QKV projection ----------------
// Grid (8 n, 32 m, 3 z): n fastest so consecutive blocks share one X m-tile (L2);
// z slowest so each 2MB weight stays L2-resident per phase.
__global__ __launch_bounds__(256) void qkv_gemm(
    const uint16_t* __restrict__ Xb,
    const uint16_t* __restrict__ WqT, const uint16_t* __restrict__ WkT,
    const uint16_t* __restrict__ WvT,
    const float* __restrict__ bq, const float* __restrict__ bk,
    const float* __restrict__ bv,
    uint16_t* __restrict__ Qo, uint16_t* __restrict__ Ko, uint16_t* __restrict__ Vt) {
  __shared__ __align__(16) uint16_t smem[17408];   // As/Bs dbuf (32KB) aliased with T
  uint16_t* As = smem;                             // [2][128][32]
  uint16_t* Bs = smem + 8192;                      // [2][128][32]
  uint16_t* T  = smem;                             // [128 ch][136] transpose buf (z==2)
  const int z = blockIdx.z;
  const uint16_t* BT  = (z == 0) ? WqT : (z == 1) ? WkT : WvT;
  const float*   bias = (z == 0) ? bq  : (z == 1) ? bk  : bv;
  const int m0 = blockIdx.y * 128, n0 = blockIdx.x * 128;
  const int lane = threadIdx.x & 63, qi = lane & 15, g = lane >> 4;
  const int wm = (threadIdx.x >> 7) & 1, wn = (threadIdx.x >> 6) & 1;
  const float l2e = 1.4426950408889634f * 0.125f;  // log2(e)/sqrt(dk), folded into Q

  const f32x4 ZERO = {0.f, 0.f, 0.f, 0.f};
  f32x4 acc[4][4];
#pragma unroll
  for (int i = 0; i < 4; i++)
#pragma unroll
    for (int j = 0; j < 4; j++) acc[i][j] = ZERO;

  if (z == 2) {
    gemm_core<false>(Xb, BT, As, Bs, m0, n0, 0, D_MODEL, acc);
    __syncthreads();  // all waves done with As/Bs before T overwrite
#pragma unroll
    for (int i = 0; i < 4; i++) {
      int tok = wm * 64 + i * 16 + g * 4;
#pragma unroll
      for (int j = 0; j < 4; j++) {
        int ch = wn * 64 + j * 16 + qi;
        float bb = bias[n0 + ch];
        uint32_t lo = (uint32_t)f2b(acc[i][j][0] + bb) | ((uint32_t)f2b(acc[i][j][1] + bb) << 16);
        uint32_t hi = (uint32_t)f2b(acc[i][j][2] + bb) | ((uint32_t)f2b(acc[i][j][3] + bb) << 16);
        uint2 pk = {lo, hi};
        *(uint2*)(T + ch * 136 + tok) = pk;
      }
    }
    __syncthreads();
    {
      int ch = threadIdx.x >> 1, sh = threadIdx.x & 1;
      const uint16_t* src = T + ch * 136 + sh * 64;
      int bidx = m0 >> 11;
      uint16_t* dst = Vt + ((size_t)(bidx * D_MODEL + n0 + ch)) * SEQ + (m0 & 2047) + sh * 64;
#pragma unroll
      for (int u = 0; u < 8; u++)
        *(uint4*)(dst + u * 8) = *(const uint4*)(src + u * 8);
    }
  } else {
    gemm_core<true>(Xb, BT, As, Bs, m0, n0, 0, D_MODEL, acc);
    uint16_t* O = z ? Ko : Qo;
    const float osc = (z == 0) ? l2e : 1.0f;
#pragma unroll
    for (int i = 0; i < 4; i++) {
      size_t tok = m0 + wm * 64 + i * 16 + qi;
#pragma unroll
      for (int j = 0; j < 4; j++) {
        int ch = n0 + wn * 64 + j * 16 + g * 4;
        float4 bb = *(const float4*)(bias + ch);
        uint32_t lo = (uint32_t)f2b((acc[i][j][0] + bb.x) * osc) |
                      ((uint32_t)f2b((acc[i][j][1] + bb.y) * osc) << 16);
        uint32_t hi = (uint32_t)f2b((acc[i][j][2] + bb.z) * osc) |
                      ((uint32_t)f2b((acc[i][j][3] + bb.w) * osc) << 16);
        uint2 pk = {lo, hi};
        *(uint2*)(O + tok * D_MODEL + ch) = pk;
      }
    }
  }
}

// -------- output projection: 128x64 tiles, n fastest (X-tile L2 sharing) --------
__global__ __launch_bounds__(256) void oproj_gemm(
    const uint16_t* __restrict__ Ab, const uint16_t* __restrict__ WoT,
    const float* __restrict__ bo, float* __restrict__ out) {
  __shared__ __align__(16) uint16_t As[8192];   // [2][128][32]
  __shared__ __align__(16) uint16_t Bs[4096];   // [2][64][32]
  const int t = threadIdx.x;
  const int lane = t & 63, qi = lane & 15, g = lane >> 4;
  const int wm = (t >> 7) & 1;                  // token-half (64 rows)
  const int wn = (t >> 6) & 1;                  // channel-half (32 cols)
  const int srow = t >> 2;
  const int sc = (t & 3) ^ ((t >> 3) & 3);
  const int wbase = t & 192;
  const int rch = (g ^ ((qi >> 1) & 3)) * 8;
  const int m0 = blockIdx.y * 128, n0 = blockIdx.x * 64;

  const uint16_t* Ag = Ab  + (size_t)(m0 + srow) * D_MODEL + sc * 8;
  const uint16_t* Bg = WoT + (size_t)(n0 + srow) * D_MODEL + sc * 8;

  const f32x4 ZERO = {0.f, 0.f, 0.f, 0.f};
  f32x4 acc[4][2];   // [token-tile][ch-tile], SWAP layout (col=token, rows=channels)
#pragma unroll
  for (int i = 0; i < 4; i++)
#pragma unroll
    for (int j = 0; j < 2; j++) acc[i][j] = ZERO;

  gl2lds16(Ag, As + wbase * 8);
  gl2lds16(Ag + (size_t)64 * D_MODEL, As + (256 + wbase) * 8);
  gl2lds16(Bg, Bs + wbase * 8);

  int cur = 0;
  for (int k0 = 0; k0 < D_MODEL; k0 += 32) {
    __syncthreads();
    int kn = k0 + 32;
    if (kn < D_MODEL) {
      int nbA = (cur ^ 1) * 4096, nbB = (cur ^ 1) * 2048;
      gl2lds16(Ag + kn, As + nbA + wbase * 8);
      gl2lds16(Ag + (size_t)64 * D_MODEL + kn, As + nbA + (256 + wbase) * 8);
      gl2lds16(Bg + kn, Bs + nbB + wbase * 8);
    }
    const uint16_t* Abuf = As + cur * 4096;
    const uint16_t* Bbuf = Bs + cur * 2048;
    bf16x8 af[4], bf[2];
#pragma unroll
    for (int i = 0; i < 4; i++)
      af[i] = *(const bf16x8*)(Abuf + (wm * 64 + i * 16 + qi) * 32 + rch);
#pragma unroll
    for (int j = 0; j < 2; j++)
      bf[j] = *(const bf16x8*)(Bbuf + (wn * 32 + j * 16 + qi) * 32 + rch);
#pragma unroll
    for (int i = 0; i < 4; i++)
#pragma unroll
      for (int j = 0; j < 2; j++)
        acc[i][j] = __builtin_amdgcn_mfma_f32_16x16x32_bf16(bf[j], af[i], acc[i][j], 0, 0, 0);
    cur ^= 1;
  }

#pragma unroll
  for (int i = 0; i < 4; i++) {
    size_t tok = m0 + wm * 64 + i * 16 + qi;
#pragma unroll
    for (int j = 0; j < 2; j++) {
      int ch = n0 + wn * 32 + j * 16 + g * 4;
      float4 bb = *(const float4*)(bo + ch);
      float4 o = {acc[i][j][0] + bb.x, acc[i][j][1] + bb.y,
                  acc[i][j][2] + bb.z, acc[i][j][3] + bb.w};
      *(float4*)(out + tok * D_MODEL + ch) = o;
    }
  }
}

// ------- flash attention: 48KB LDS (3 blocks/CU), K/V dbuf, Ps aliases Q staging -------
// Q frags hoisted to regs after initial barrier; a second barrier then frees the
// Q region for Ps ([128 q][64 kk], even-XOR chunk swizzle keyed on row&7 — writer
// and reader of row q both have qi=q&15, so keys agree; 16B read contiguity kept).
__global__ __launch_bounds__(256) void attn_fwd(
    const uint16_t* __restrict__ Q, const uint16_t* __restrict__ K,
    const uint16_t* __restrict__ Vt, uint16_t* __restrict__ O) {
  __shared__ __align__(16) uint16_t sm[24576];   // 49152 B -> 3 blocks/CU
  // K bufs: [0,8192) = buf*4096 + ks*2048; V bufs: [8192,16384);
  // [16384,24576): Q staging (two [128][32] halves), then Ps [128][64] swizzled.
  uint16_t* Ps = sm + 16384;

  const int t = threadIdx.x, lane = t & 63, w = t >> 6;
  const int g = lane >> 4, qi = lane & 15;
  const int wbase = t & 192;
  const int sc = (t & 3) ^ ((t >> 3) & 3);
  const int rch = (g ^ ((qi >> 1) & 3)) * 8;
  const int key = qi & 7;                        // Ps swizzle key (= row&7)
  const int q0 = blockIdx.x * 128;
  const int bh = blockIdx.y, b = bh >> 4, h = bh & 15;
  const uint16_t* Qp = Q + (size_t)b * SEQ * D_MODEL + h * DKH;
  const uint16_t* Kp = K + (size_t)b * SEQ * D_MODEL + h * DKH;
  const uint16_t* Vp = Vt + (size_t)bh * DKH * SEQ;

  const int srow = t >> 2, c8 = sc * 8;

  // stage Q (into the region Ps will later reuse) + K/V tile 0 into buf 0
#pragma unroll
  for (int hs = 0; hs < 2; hs++)
#pragma unroll
    for (int j = 0; j < 2; j++)
      gl2lds16(Qp + (size_t)(q0 + j * 64 + srow) * D_MODEL + hs * 32 + c8,
               sm + 16384 + hs * 4096 + (j * 256 + wbase) * 8);
  {
    const uint16_t* Kr = Kp + (size_t)srow * D_MODEL;
    const uint16_t* Vr = Vp + (size_t)srow * SEQ;
    gl2lds16(Kr + c8,      sm + wbase * 8);
    gl2lds16(Kr + 32 + c8, sm + 2048 + wbase * 8);
    gl2lds16(Vr + c8,      sm + 8192 + wbase * 8);
    gl2lds16(Vr + 32 + c8, sm + 8192 + 2048 + wbase * 8);
  }
  __syncthreads();   // Q + buf0 visible

  // hoist Q fragments into registers (reused all 32 iterations)
  bf16x8 qf[2][2];
#pragma unroll
  for (int ks = 0; ks < 2; ks++)
#pragma unroll
    for (int i = 0; i < 2; i++)
      qf[ks][i] = *(const bf16x8*)(sm + 16384 + ks * 4096 + (w * 32 + i * 16 + qi) * 32 + rch);
  __syncthreads();   // all qf hoisted before any wave's Ps writes overwrite Q

  float lsum[2] = {0.f, 0.f};
  const f32x4 ZERO = {0.f, 0.f, 0.f, 0.f};
  f32x4 oaccT[4][2];   // [d-tile][q-tile]
#pragma unroll
  for (int d = 0; d < 4; d++)
#pragma unroll
    for (int i = 0; i < 2; i++) oaccT[d][i] = ZERO;

  int cur = 0;
  for (int kt = 0; kt < SEQ / 64; kt++) {
    // prefetch next K/V tile into the other buffer (in flight across this compute)
    if (kt + 1 < SEQ / 64) {
      int nb = (cur ^ 1) * 4096;
      const uint16_t* Kr = Kp + (size_t)((kt + 1) * 64 + srow) * D_MODEL;
      const uint16_t* Vr = Vp + (size_t)srow * SEQ + (kt + 1) * 64;
      gl2lds16(Kr + c8,      sm + nb + wbase * 8);
      gl2lds16(Kr + 32 + c8, sm + nb + 2048 + wbase * 8);
      gl2lds16(Vr + c8,      sm + 8192 + nb + wbase * 8);
      gl2lds16(Vr + 32 + c8, sm + 8192 + nb + 2048 + wbase * 8);
    }
    const uint16_t* Kb = sm + cur * 4096;
    const uint16_t* Vb = sm + 8192 + cur * 4096;

    // S^T[kk][q] = K Q^T
    f32x4 sacc[4][2];
#pragma unroll
    for (int j = 0; j < 4; j++)
#pragma unroll
      for (int i = 0; i < 2; i++) sacc[j][i] = ZERO;
#pragma unroll
    for (int ks = 0; ks < 2; ks++) {
      const uint16_t* Ksb = Kb + ks * 2048;
      bf16x8 kf[4];
#pragma unroll
      for (int j = 0; j < 4; j++)
        kf[j] = *(const bf16x8*)(Ksb + (j * 16 + qi) * 32 + rch);
#pragma unroll
      for (int j = 0; j < 4; j++)
#pragma unroll
        for (int i = 0; i < 2; i++)
          sacc[j][i] = __builtin_amdgcn_mfma_f32_16x16x32_bf16(kf[j], qf[ks][i], sacc[j][i], 0, 0, 0);
    }

    // P = exp2(s); pack bf16 (RTZ via v_perm); swizzled b64 stores; l sums fp32 p
#pragma unroll
    for (int i = 0; i < 2; i++) {
      uint16_t* Pr = Ps + (w * 32 + i * 16 + qi) * 64;
#pragma unroll
      for (int j = 0; j < 4; j++) {
        float p0 = __builtin_amdgcn_exp2f(sacc[j][i][0]);
        float p1 = __builtin_amdgcn_exp2f(sacc[j][i][1]);
        float p2 = __builtin_amdgcn_exp2f(sacc[j][i][2]);
        float p3 = __builtin_amdgcn_exp2f(sacc[j][i][3]);
        lsum[i] += (p0 + p1) + (p2 + p3);
        uint2 pk = {__builtin_amdgcn_perm(__builtin_bit_cast(uint32_t, p1),
                                          __builtin_bit_cast(uint32_t, p0), 0x07060302u),
                    __builtin_amdgcn_perm(__builtin_bit_cast(uint32_t, p3),
                                          __builtin_bit_cast(uint32_t, p2), 0x07060302u)};
        *(uint2*)(Pr + (((j * 4 + g) ^ (2 * key)) << 2)) = pk;
      }
    }
    // no barrier: P round-trip is wave-local (same q-rows written & read by wave w)

    // O^T[d][q] += V^T P^T
#pragma unroll
    for (int ks = 0; ks < 2; ks++) {
      const uint16_t* Vsb = Vb + ks * 2048;
      bf16x8 vf[4], pf[2];
#pragma unroll
      for (int d = 0; d < 4; d++)
        vf[d] = *(const bf16x8*)(Vsb + (d * 16 + qi) * 32 + rch);
#pragma unroll
      for (int i = 0; i < 2; i++)
        pf[i] = *(const bf16x8*)(Ps + (w * 32 + i * 16 + qi) * 64 +
                                 (((ks * 4 + g) ^ key) << 3));
#pragma unroll
      for (int d = 0; d < 4; d++)
#pragma unroll
        for (int i = 0; i < 2; i++)
          oaccT[d][i] = __builtin_amdgcn_mfma_f32_16x16x32_bf16(vf[d], pf[i], oaccT[d][i], 0, 0, 0);
    }

    if (kt + 1 < SEQ / 64) __syncthreads();  // publish prefetched buffer; reads of cur done
    cur ^= 1;
  }

  // final l reduction over the 4 lane-groups holding the same q
#pragma unroll
  for (int i = 0; i < 2; i++) {
    lsum[i] += __shfl_xor(lsum[i], 16, 64);
    lsum[i] += __shfl_xor(lsum[i], 32, 64);
  }
  float rl[2] = {1.f / lsum[0], 1.f / lsum[1]};

  // epilogue: O[q][h*64+d] = O^T/l (RNE), 4 consecutive d per 8B store
#pragma unroll
  for (int i = 0; i < 2; i++) {
    size_t row = (size_t)b * SEQ + q0 + w * 32 + i * 16 + qi;
#pragma unroll
    for (int d = 0; d < 4; d++) {
      uint32_t lo = (uint32_t)f2b(oaccT[d][i][0] * rl[i]) |
                    ((uint32_t)f2b(oaccT[d][i][1] * rl[i]) << 16);
      uint32_t hi = (uint32_t)f2b(oaccT[d][i][2] * rl[i]) |
                    ((uint32_t)f2b(oaccT[d][i][3] * rl[i]) << 16);
      uint2 pk = {lo, hi};
      *(uint2*)(O + row * D_MODEL + h * DKH + d * 16 + g * 4) = pk;
    }
  }
}

extern "C" void kernel_launch(void* const* d_in, const int* in_sizes, int n_in,
                              void* d_out, int out_size, void* d_ws, size_t ws_size,
                              hipStream_t stream) {
  (void)in_sizes; (void)n_in; (void)out_size; (void)ws_size;
  const float* X  = (const float*)d_in[0];
  const float* Wq = (const float*)d_in[1];
  const float* bq = (const float*)d_in[2];
  const float* Wk = (const float*)d_in[3];
  const float* bk = (const float*)d_in[4];
  const float* Wv = (const float*)d_in[5];
  const float* bv = (const float*)d_in[6];
  const float* Wo = (const float*)d_in[7];
  const float* bo = (const float*)d_in[8];
  float* out = (float*)d_out;

  char* p = (char*)d_ws;
  uint16_t* Xb  = (uint16_t*)p; p += (size_t)M_TOK * D_MODEL * 2;
  uint16_t* WqT = (uint16_t*)p; p += (size_t)D_MODEL * D_MODEL * 2;
  uint16_t* WkT = (uint16_t*)p; p += (size_t)D_MODEL * D_MODEL * 2;
  uint16_t* WvT = (uint16_t*)p; p += (size_t)D_MODEL * D_MODEL * 2;
  uint16_t* WoT = (uint16_t*)p; p += (size_t)D_MODEL * D_MODEL * 2;
  uint16_t* Qw  = (uint16_t*)p; p += (size_t)M_TOK * D_MODEL * 2;
  uint16_t* Kw  = (uint16_t*)p; p += (size_t)M_TOK * D_MODEL * 2;
  uint16_t* Vt  = (uint16_t*)p; p += (size_t)M_TOK * D_MODEL * 2;
  uint16_t* Ob  = (uint16_t*)p; p += (size_t)M_TOK * D_MODEL * 2;

  convx<<<(M_TOK * D_MODEL) / (256 * 8), 256, 0, stream>>>(X, Xb);
  wtrans<<<dim3(32, 32, 4), dim3(32, 32), 0, stream>>>(Wq, Wk, Wv, Wo, WqT, WkT, WvT, WoT);
  qkv_gemm<<<dim3(8, 32, 3), 256, 0, stream>>>(Xb, WqT, WkT, WvT, bq, bk, bv, Qw, Kw, Vt);
  attn_fwd<<<dim3(SEQ / 128, BATCH * NH), 256, 0, stream>>>(Qw, Kw, Vt, Ob);
  oproj_gemm<<<dim3(16, 32), 256, 0, stream>>>(Ob, WoT, bo, out);
}